// Round 6
// baseline (24167.281 us; speedup 1.0000x reference)
//
#include <hip/hip_runtime.h>
#include <hip/hip_bf16.h>
#include <cmath>

// Problem: N=64, T=512, D=512, H=512
//   xw = x @ Wx + b                 (parallel GEMM, kernel A -> d_out)
//   h_t = tanh(xw_t + h_{t-1} @ Wh) (sequential, kernel B)
//
// R6: same 4-wgs/seq register-resident-Wh structure as R5, but the per-step
// h exchange moves from the L3 coherence point (~800cy RTT, R5's bottleneck:
// VALUBusy 23%, 2500cy/step of pure wait) to the XCD-local L2 (~200cy RTT):
//  - producers DUAL-PUBLISH each tagged 8B {tag,h} word: hbufA via sc0 store
//    (lands in the producer XCD's L2; all 4 wgs of a seq share an XCD under
//    round-robin dispatch) and hbufB via relaxed agent-scope atomic (L3,
//    guaranteed visible device-wide). Disjoint buffers => no hazard where a
//    stale L2 eviction overwrites a newer L3 value.
//  - consumers poll hbufA with sc0 loads (L1-bypass, L2-hit). At t=0 a small
//    poll cap (600) detects "partner not on my XCD"; on timeout the wave
//    permanently switches to polling hbufB (agent atomics). Tags are
//    monotonic, so the fast path can only succeed-with-correct-data or time
//    out -- never return wrong data. Hang-proof: worst case = R5 speed.

#define DH     512
#define NSEQ   64
#define TSTEPS 512
#define MTOT   32768   // N*T

typedef float v2f __attribute__((ext_vector_type(2)));

// ---------------- Kernel A: xw = x @ Wx + b  (fp32 LDS-tiled GEMM) ----------
__global__ __launch_bounds__(256) void xw_gemm(
    const float* __restrict__ X,    // (32768, 512)
    const float* __restrict__ Wx,   // (512, 512)
    const float* __restrict__ b,    // (512,)
    float* __restrict__ XW)         // (32768, 512) == d_out
{
    __shared__ float As[16][64];
    __shared__ float Bs[16][64];

    const int bm = blockIdx.x * 64;
    const int bn = blockIdx.y * 64;
    const int tid = threadIdx.x;
    const int tr = tid >> 4;
    const int tc = tid & 15;

    float acc[4][4] = {};

    for (int k0 = 0; k0 < DH; k0 += 16) {
        {
            int m  = tid >> 2;
            int kk = (tid & 3) * 4;
            const float4 v = *(const float4*)&X[(size_t)(bm + m) * DH + k0 + kk];
            As[kk + 0][m] = v.x; As[kk + 1][m] = v.y;
            As[kk + 2][m] = v.z; As[kk + 3][m] = v.w;
        }
        {
            int k  = tid >> 4;
            int j4 = (tid & 15) * 4;
            *(float4*)&Bs[k][j4] = *(const float4*)&Wx[(size_t)(k0 + k) * DH + bn + j4];
        }
        __syncthreads();

        #pragma unroll
        for (int k = 0; k < 16; ++k) {
            float a0 = As[k][tr * 4 + 0], a1 = As[k][tr * 4 + 1];
            float a2 = As[k][tr * 4 + 2], a3 = As[k][tr * 4 + 3];
            float b0 = Bs[k][tc * 4 + 0], b1 = Bs[k][tc * 4 + 1];
            float b2 = Bs[k][tc * 4 + 2], b3 = Bs[k][tc * 4 + 3];
            acc[0][0] += a0 * b0; acc[0][1] += a0 * b1; acc[0][2] += a0 * b2; acc[0][3] += a0 * b3;
            acc[1][0] += a1 * b0; acc[1][1] += a1 * b1; acc[1][2] += a1 * b2; acc[1][3] += a1 * b3;
            acc[2][0] += a2 * b0; acc[2][1] += a2 * b1; acc[2][2] += a2 * b2; acc[2][3] += a2 * b3;
            acc[3][0] += a3 * b0; acc[3][1] += a3 * b1; acc[3][2] += a3 * b2; acc[3][3] += a3 * b3;
        }
        __syncthreads();
    }

    #pragma unroll
    for (int i = 0; i < 4; ++i) {
        const size_t row = (size_t)(bm + tr * 4 + i);
        #pragma unroll
        for (int j = 0; j < 4; ++j) {
            const int col = bn + tc * 4 + j;
            XW[row * DH + col] = acc[i][j] + b[col];
        }
    }
}

// ---------------- Kernel B (R6) ---------------------------------------------
// 512 thr = 8 waves. lane = tid&63, s = tid>>6.
// Wave s: FMA partials for the wg's 128 cols over k in [s*64, s*64+64);
//   weights v2f wv[64] register-resident (pinned).
// Reducer waves (s = 2*part + r): their FMA k-slice equals their own reduce
//   output slice -> own h never leaves the wg.
// Remote waves: lane polls tagged slot s*64+lane (L2 fast path w/ L3 backup).
__global__ __launch_bounds__(512, 2) void rnn_rec6(
    const float* __restrict__ Wh,             // (512, 512)
    const float* __restrict__ h0,             // (64, 512)
    float* __restrict__ out,                  // (64, 512, 512); xw on entry
    unsigned long long* __restrict__ hbufA,   // (2,64,512) L2-path tagged h
    unsigned long long* __restrict__ hbufB)   // (2,64,512) L3-path tagged h
{
    __shared__ float hslice[8][64];          // wave-private h slices
    __shared__ float partb[2][8][128];       // double-buffered partials

    const int bid  = blockIdx.x;
    // all 4 parts of a seq share bid&7 -> same XCD under round-robin dispatch
    const int xcd  = bid & 7;
    const int idx  = bid >> 3;
    const int seq  = xcd * 8 + (idx & 7);
    const int part = idx >> 3;               // 0..3
    const int tid  = threadIdx.x;
    const int lane = tid & 63;
    const int s    = tid >> 6;                // wave 0..7
    const int colbase = part * 128;
    const int c0   = colbase + lane * 2;

    // ---- one-time: weight slice into registers, pinned ----
    v2f wv[64];
    #pragma unroll
    for (int k = 0; k < 64; ++k)
        wv[k] = *(const v2f*)&Wh[(size_t)(s * 64 + k) * DH + c0];
    #pragma unroll
    for (int k = 0; k < 64; ++k)
        asm volatile("" : "+v"(wv[k]));

    const int rwave = s - 2 * part;
    const bool is_reducer = (rwave == 0) | (rwave == 1);
    const int q     = rwave * 64 + lane;      // col idx within part (reducer)
    const int mycol = colbase + q;            // global col (reducer)
    const int slot  = s * 64 + lane;          // h index this lane feeds

    hslice[s][lane] = h0[(size_t)seq * DH + slot];

    float* __restrict__ outn = out + (size_t)seq * TSTEPS * DH;
    float xw_cur = is_reducer ? outn[mycol] : 0.0f;

    unsigned long long* __restrict__ aA0 = &hbufA[((size_t)0 * NSEQ + seq) * DH];
    unsigned long long* __restrict__ aA1 = &hbufA[((size_t)1 * NSEQ + seq) * DH];
    unsigned long long* __restrict__ aB0 = &hbufB[((size_t)0 * NSEQ + seq) * DH];
    unsigned long long* __restrict__ aB1 = &hbufB[((size_t)1 * NSEQ + seq) * DH];

    bool useL3 = false;

    for (int t = 0; t < TSTEPS; ++t) {
        const int buf = t & 1;

        // ---- phase A: partial FMA over own k-slice (all 8 waves) ----
        v2f acc = {0.0f, 0.0f};
        #pragma unroll
        for (int qq = 0; qq < 16; ++qq) {
            const float4 h4 = *(const float4*)&hslice[s][qq * 4];
            v2f hb;
            hb.x = h4.x; hb.y = h4.x; acc = __builtin_elementwise_fma(hb, wv[4*qq+0], acc);
            hb.x = h4.y; hb.y = h4.y; acc = __builtin_elementwise_fma(hb, wv[4*qq+1], acc);
            hb.x = h4.z; hb.y = h4.z; acc = __builtin_elementwise_fma(hb, wv[4*qq+2], acc);
            hb.x = h4.w; hb.y = h4.w; acc = __builtin_elementwise_fma(hb, wv[4*qq+3], acc);
        }
        *(v2f*)&partb[buf][s][lane * 2] = acc;
        __syncthreads();   // the only barrier per step

        unsigned long long* hbA = buf ? aA1 : aA0;
        unsigned long long* hbB = buf ? aB1 : aB0;

        if (is_reducer) {
            float ssum = partb[buf][0][q] + partb[buf][1][q]
                       + partb[buf][2][q] + partb[buf][3][q]
                       + partb[buf][4][q] + partb[buf][5][q]
                       + partb[buf][6][q] + partb[buf][7][q];
            const float hval = tanhf(xw_cur + ssum);
            if (t < TSTEPS - 1) {
                const unsigned long long v =
                    ((unsigned long long)(unsigned)(t + 1) << 32) |
                    (unsigned long long)__float_as_uint(hval);
                // L2 fast publish (same-XCD consumers see it in ~200cy)
                asm volatile("global_store_dwordx2 %0, %1, off sc0"
                             :: "v"((unsigned long long)(uintptr_t)(hbA + mycol)),
                                "v"(v) : "memory");
                // L3 guaranteed publish (cross-XCD / safety path)
                __hip_atomic_store(&hbB[mycol], v,
                                   __ATOMIC_RELAXED, __HIP_MEMORY_SCOPE_AGENT);
            }
            hslice[s][lane] = hval;           // own next-step data (slot==mycol)
            outn[(size_t)t * DH + mycol] = hval;
            if (t < TSTEPS - 1)
                xw_cur = outn[(size_t)(t + 1) * DH + mycol];
        } else if (t < TSTEPS - 1) {
            const unsigned want = (unsigned)(t + 1);
            unsigned long long v = 0;
            bool got = false;
            if (!useL3) {
                const unsigned long long a =
                    (unsigned long long)(uintptr_t)(hbA + slot);
                // t=0: small cap to detect cross-XCD placement; later: large
                // safety cap (never hit in practice once the path proved out).
                int cap = (t == 0) ? 600 : (1 << 17);
                do {
                    asm volatile("global_load_dwordx2 %0, %1, off sc0\n\t"
                                 "s_waitcnt vmcnt(0)"
                                 : "=v"(v) : "v"(a) : "memory");
                    got = ((unsigned)(v >> 32) >= want);
                } while (!got && --cap > 0);
                if (__any(!got)) useL3 = true;   // wave-uniform switch
            }
            if (useL3 && !got) {
                do {
                    v = __hip_atomic_load(&hbB[slot], __ATOMIC_RELAXED,
                                          __HIP_MEMORY_SCOPE_AGENT);
                } while ((unsigned)(v >> 32) < want);
            }
            hslice[s][lane] = __uint_as_float((unsigned)v);
        }
        // no second barrier: hslice wave-private, partb double-buffered
    }
}

// ---------------- Mid fallback (R5 kernel, L3-only) if ws in [512K,1M) ------
__global__ __launch_bounds__(512, 2) void rnn_rec5(
    const float* __restrict__ Wh,
    const float* __restrict__ h0,
    float* __restrict__ out,
    unsigned long long* __restrict__ hbuf)
{
    __shared__ float hslice[8][64];
    __shared__ float partb[2][8][128];

    const int bid  = blockIdx.x;
    const int xcd  = bid & 7;
    const int idx  = bid >> 3;
    const int seq  = xcd * 8 + (idx & 7);
    const int part = idx >> 3;
    const int tid  = threadIdx.x;
    const int lane = tid & 63;
    const int s    = tid >> 6;
    const int colbase = part * 128;
    const int c0   = colbase + lane * 2;

    v2f wv[64];
    #pragma unroll
    for (int k = 0; k < 64; ++k)
        wv[k] = *(const v2f*)&Wh[(size_t)(s * 64 + k) * DH + c0];
    #pragma unroll
    for (int k = 0; k < 64; ++k)
        asm volatile("" : "+v"(wv[k]));

    const int rwave = s - 2 * part;
    const bool is_reducer = (rwave == 0) | (rwave == 1);
    const int q     = rwave * 64 + lane;
    const int mycol = colbase + q;
    const int slot  = s * 64 + lane;

    hslice[s][lane] = h0[(size_t)seq * DH + slot];

    float* __restrict__ outn = out + (size_t)seq * TSTEPS * DH;
    float xw_cur = is_reducer ? outn[mycol] : 0.0f;

    for (int t = 0; t < TSTEPS; ++t) {
        const int buf = t & 1;
        v2f acc = {0.0f, 0.0f};
        #pragma unroll
        for (int qq = 0; qq < 16; ++qq) {
            const float4 h4 = *(const float4*)&hslice[s][qq * 4];
            v2f hb;
            hb.x = h4.x; hb.y = h4.x; acc = __builtin_elementwise_fma(hb, wv[4*qq+0], acc);
            hb.x = h4.y; hb.y = h4.y; acc = __builtin_elementwise_fma(hb, wv[4*qq+1], acc);
            hb.x = h4.z; hb.y = h4.z; acc = __builtin_elementwise_fma(hb, wv[4*qq+2], acc);
            hb.x = h4.w; hb.y = h4.w; acc = __builtin_elementwise_fma(hb, wv[4*qq+3], acc);
        }
        *(v2f*)&partb[buf][s][lane * 2] = acc;
        __syncthreads();

        unsigned long long* hb64 = &hbuf[((size_t)buf * NSEQ + seq) * DH];
        if (is_reducer) {
            float ssum = partb[buf][0][q] + partb[buf][1][q]
                       + partb[buf][2][q] + partb[buf][3][q]
                       + partb[buf][4][q] + partb[buf][5][q]
                       + partb[buf][6][q] + partb[buf][7][q];
            const float hval = tanhf(xw_cur + ssum);
            if (t < TSTEPS - 1) {
                const unsigned long long v =
                    ((unsigned long long)(unsigned)(t + 1) << 32) |
                    (unsigned long long)__float_as_uint(hval);
                __hip_atomic_store(&hb64[mycol], v,
                                   __ATOMIC_RELAXED, __HIP_MEMORY_SCOPE_AGENT);
            }
            hslice[s][lane] = hval;
            outn[(size_t)t * DH + mycol] = hval;
            if (t < TSTEPS - 1)
                xw_cur = outn[(size_t)(t + 1) * DH + mycol];
        } else if (t < TSTEPS - 1) {
            unsigned long long v;
            do {
                v = __hip_atomic_load(&hb64[slot], __ATOMIC_RELAXED,
                                      __HIP_MEMORY_SCOPE_AGENT);
            } while ((unsigned)(v >> 32) < (unsigned)(t + 1));
            hslice[s][lane] = __uint_as_float((unsigned)v);
        }
    }
}

// ---------------- Last-resort fallback (R1 kernel) --------------------------
__global__ __launch_bounds__(1024) void rnn_rec(
    const float* __restrict__ Wh,
    const float* __restrict__ h0,
    float* __restrict__ out)
{
    __shared__ float hsh[DH];
    __shared__ float part[8][DH];

    const int n     = blockIdx.x;
    const int tid   = threadIdx.x;
    const int jgrp  = tid & 127;
    const int ks    = tid >> 7;
    const int kbase = ks * 64;

    if (tid < DH) hsh[tid] = h0[(size_t)n * DH + tid];
    __syncthreads();

    const float4* __restrict__ Wh4 = (const float4*)Wh;
    float* __restrict__ outn = out + (size_t)n * TSTEPS * DH;

    float xw_cur = (tid < DH) ? outn[tid] : 0.0f;

    for (int t = 0; t < TSTEPS; ++t) {
        float xw_next = 0.0f;
        if (tid < DH && t < TSTEPS - 1) xw_next = outn[(size_t)(t + 1) * DH + tid];

        float4 acc = {0.0f, 0.0f, 0.0f, 0.0f};
        #pragma unroll 8
        for (int k = 0; k < 64; ++k) {
            const float hk = hsh[kbase + k];
            const float4 w = Wh4[(size_t)(kbase + k) * 128 + jgrp];
            acc.x += hk * w.x; acc.y += hk * w.y;
            acc.z += hk * w.z; acc.w += hk * w.w;
        }
        *(float4*)&part[ks][jgrp * 4] = acc;
        __syncthreads();

        if (tid < DH) {
            const int j = tid;
            float sum = part[0][j] + part[1][j] + part[2][j] + part[3][j]
                      + part[4][j] + part[5][j] + part[6][j] + part[7][j];
            const float hv = tanhf(xw_cur + sum);
            hsh[j] = hv;
            outn[(size_t)t * DH + j] = hv;
            xw_cur = xw_next;
        }
        __syncthreads();
    }
}

extern "C" void kernel_launch(void* const* d_in, const int* in_sizes, int n_in,
                              void* d_out, int out_size, void* d_ws, size_t ws_size,
                              hipStream_t stream) {
    const float* x  = (const float*)d_in[0];  // (64, 512, 512)
    const float* h0 = (const float*)d_in[1];  // (64, 512)
    const float* Wx = (const float*)d_in[2];  // (512, 512)
    const float* Wh = (const float*)d_in[3];  // (512, 512)
    const float* b  = (const float*)d_in[4];  // (512,)
    float* out = (float*)d_out;               // (64, 512, 512)

    // Kernel A: xw = x @ Wx + b, written into d_out.
    xw_gemm<<<dim3(MTOT / 64, DH / 64), 256, 0, stream>>>(x, Wx, b, out);

    // Workspace: hbufA | hbufB, each (2,64,512) u64 = 512 KB. Zeroed per
    // launch so step-0 polls see tag 0 < 1 (graph-replay deterministic).
    const size_t one = (size_t)2 * NSEQ * DH * sizeof(unsigned long long);
    if (ws_size >= 2 * one) {
        unsigned long long* hbufA = (unsigned long long*)d_ws;
        unsigned long long* hbufB = hbufA + 2 * NSEQ * DH;
        hipMemsetAsync(d_ws, 0, 2 * one, stream);
        rnn_rec6<<<256, 512, 0, stream>>>(Wh, h0, out, hbufA, hbufB);
    } else if (ws_size >= one) {
        unsigned long long* hbuf = (unsigned long long*)d_ws;
        hipMemsetAsync(hbuf, 0, one, stream);
        rnn_rec5<<<256, 512, 0, stream>>>(Wh, h0, out, hbuf);
    } else {
        rnn_rec<<<NSEQ, 1024, 0, stream>>>(Wh, h0, out);
    }
}

// Round 7
// 1340.468 us; speedup vs baseline: 18.0290x; 18.0290x over previous
//
#include <hip/hip_runtime.h>
#include <hip/hip_bf16.h>
#include <cmath>

// Problem: N=64, T=512, D=512, H=512
//   xw = x @ Wx + b                 (parallel GEMM, kernel A -> d_out)
//   h_t = tanh(xw_t + h_{t-1} @ Wh) (sequential, kernel B)
//
// R7: latency-HIDING, not latency-reduction (R6's L2 fast path is refuted:
// sc0 loads spin on stale L1 -> 24 ms disaster; reverted to the proven
// relaxed-agent-atomic L3 exchange). Each wg now owns TWO sequences with the
// SAME 128-col Wh slice (register-resident, as R5). Per step: task0 (seq A)
// then task1 (seq B). A seq's remote h pieces are needed one full task
// (~550 cyc) after the siblings publish them, and the tagged slot is
// PREFETCHED (load issued right after the previous publish, checked one task
// later), so the L3 transit+discovery (~2650 cyc naked in R5) overlaps with
// the other sequence's FMA/reduce. Steady-state period ~= transit + task
// instead of transit + discovery + task.

#define DH     512
#define NSEQ   64
#define TSTEPS 512
#define MTOT   32768   // N*T

typedef float v2f __attribute__((ext_vector_type(2)));

// ---------------- Kernel A: xw = x @ Wx + b  (fp32 LDS-tiled GEMM) ----------
__global__ __launch_bounds__(256) void xw_gemm(
    const float* __restrict__ X,    // (32768, 512)
    const float* __restrict__ Wx,   // (512, 512)
    const float* __restrict__ b,    // (512,)
    float* __restrict__ XW)         // (32768, 512) == d_out
{
    __shared__ float As[16][64];
    __shared__ float Bs[16][64];

    const int bm = blockIdx.x * 64;
    const int bn = blockIdx.y * 64;
    const int tid = threadIdx.x;
    const int tr = tid >> 4;
    const int tc = tid & 15;

    float acc[4][4] = {};

    for (int k0 = 0; k0 < DH; k0 += 16) {
        {
            int m  = tid >> 2;
            int kk = (tid & 3) * 4;
            const float4 v = *(const float4*)&X[(size_t)(bm + m) * DH + k0 + kk];
            As[kk + 0][m] = v.x; As[kk + 1][m] = v.y;
            As[kk + 2][m] = v.z; As[kk + 3][m] = v.w;
        }
        {
            int k  = tid >> 4;
            int j4 = (tid & 15) * 4;
            *(float4*)&Bs[k][j4] = *(const float4*)&Wx[(size_t)(k0 + k) * DH + bn + j4];
        }
        __syncthreads();

        #pragma unroll
        for (int k = 0; k < 16; ++k) {
            float a0 = As[k][tr * 4 + 0], a1 = As[k][tr * 4 + 1];
            float a2 = As[k][tr * 4 + 2], a3 = As[k][tr * 4 + 3];
            float b0 = Bs[k][tc * 4 + 0], b1 = Bs[k][tc * 4 + 1];
            float b2 = Bs[k][tc * 4 + 2], b3 = Bs[k][tc * 4 + 3];
            acc[0][0] += a0 * b0; acc[0][1] += a0 * b1; acc[0][2] += a0 * b2; acc[0][3] += a0 * b3;
            acc[1][0] += a1 * b0; acc[1][1] += a1 * b1; acc[1][2] += a1 * b2; acc[1][3] += a1 * b3;
            acc[2][0] += a2 * b0; acc[2][1] += a2 * b1; acc[2][2] += a2 * b2; acc[2][3] += a2 * b3;
            acc[3][0] += a3 * b0; acc[3][1] += a3 * b1; acc[3][2] += a3 * b2; acc[3][3] += a3 * b3;
        }
        __syncthreads();
    }

    #pragma unroll
    for (int i = 0; i < 4; ++i) {
        const size_t row = (size_t)(bm + tr * 4 + i);
        #pragma unroll
        for (int j = 0; j < 4; ++j) {
            const int col = bn + tc * 4 + j;
            XW[row * DH + col] = acc[i][j] + b[col];
        }
    }
}

// ---------------- Kernel B (R7): 2 seqs/wg, pipelined L3 exchange -----------
// 128 wgs x 512 thr. wg: part = bid&3 (128-col slice), pair g = bid>>2,
// seqs {2g, 2g+1}. Waves: lane=tid&63, s=tid>>6; wave s holds Wh k-slice
// [s*64,+64) x 128 cols in regs (v2f wv[64], pinned). Reducer waves
// (s==2*part, 2*part+1) reduce+tanh+publish; their own h piece never leaves
// the wg (slot == mycol identity). Remote waves poll 1 tagged slot per seq.
// Step = task0 -> task1; each fill's tagged load is prefetched one task
// ahead, so L3 transit hides under the other task's compute.
__global__ __launch_bounds__(512, 2) void rnn_rec7(
    const float* __restrict__ Wh,            // (512, 512)
    const float* __restrict__ h0,            // (64, 512)
    float* __restrict__ out,                 // (64, 512, 512); xw on entry
    unsigned long long* __restrict__ hbuf)   // (2, 64, 512) tagged h (d_ws)
{
    __shared__ float hslice[2][8][64];       // [seq][wave][lane] wave-private
    __shared__ float partb[2][8][128];       // [task][wave][col]

    const int bid  = blockIdx.x;             // 0..127
    const int part = bid & 3;
    const int g    = bid >> 2;               // 0..31
    const int seq0 = g * 2;
    const int seq1 = seq0 + 1;
    const int tid  = threadIdx.x;
    const int lane = tid & 63;
    const int s    = tid >> 6;               // wave 0..7
    const int colbase = part * 128;
    const int c0   = colbase + lane * 2;

    // ---- one-time: weight slice into registers, pinned ----
    v2f wv[64];
    #pragma unroll
    for (int k = 0; k < 64; ++k)
        wv[k] = *(const v2f*)&Wh[(size_t)(s * 64 + k) * DH + c0];
    #pragma unroll
    for (int k = 0; k < 64; ++k)
        asm volatile("" : "+v"(wv[k]));

    const int rwave = s - 2 * part;
    const bool is_reducer = (rwave == 0) | (rwave == 1);
    const int q     = rwave * 64 + lane;     // col within part (reducer only)
    const int mycol = colbase + q;           // == slot for reducer waves
    const int slot  = s * 64 + lane;         // h index this lane feeds

    hslice[0][s][lane] = h0[(size_t)seq0 * DH + slot];
    hslice[1][s][lane] = h0[(size_t)seq1 * DH + slot];

    float* __restrict__ o0 = out + (size_t)seq0 * TSTEPS * DH;
    float* __restrict__ o1 = out + (size_t)seq1 * TSTEPS * DH;
    float xw0 = is_reducer ? o0[mycol] : 0.0f;
    float xw1 = is_reducer ? o1[mycol] : 0.0f;

    unsigned long long* const b0s0 = &hbuf[((size_t)0 * NSEQ + seq0) * DH];
    unsigned long long* const b1s0 = &hbuf[((size_t)1 * NSEQ + seq0) * DH];
    unsigned long long* const b0s1 = &hbuf[((size_t)0 * NSEQ + seq1) * DH];
    unsigned long long* const b1s1 = &hbuf[((size_t)1 * NSEQ + seq1) * DH];

    unsigned long long pf0 = 0, pf1 = 0;     // prefetched tagged words
    __syncthreads();

    for (int t = 0; t < TSTEPS; ++t) {
        const int buf = t & 1;               // h_t publish buffer
        const unsigned wantP = (unsigned)t;  // tag of h_{t-1}
        unsigned long long* const pb0 = buf ? b0s0 : b1s0;  // holds h_{t-1}
        unsigned long long* const pb1 = buf ? b0s1 : b1s1;
        unsigned long long* const cb0 = buf ? b1s0 : b0s0;  // h_t target
        unsigned long long* const cb1 = buf ? b1s1 : b0s1;

        // ---- fill0: hslice[0] <- h_{t-1}(seq0); also issue pf1 ----
        if (t > 0 && !is_reducer) {
            pf1 = __hip_atomic_load(&pb1[slot], __ATOMIC_RELAXED,
                                    __HIP_MEMORY_SCOPE_AGENT);
            unsigned long long v = pf0;
            while ((unsigned)(v >> 32) < wantP)
                v = __hip_atomic_load(&pb0[slot], __ATOMIC_RELAXED,
                                      __HIP_MEMORY_SCOPE_AGENT);
            hslice[0][s][lane] = __uint_as_float((unsigned)v);
        }

        // ---- task0 FMA: partials for seq0 over own k-slice ----
        {
            v2f acc = {0.0f, 0.0f};
            #pragma unroll
            for (int qq = 0; qq < 16; ++qq) {
                const float4 h4 = *(const float4*)&hslice[0][s][qq * 4];
                v2f hb;
                hb.x = h4.x; hb.y = h4.x; acc = __builtin_elementwise_fma(hb, wv[4*qq+0], acc);
                hb.x = h4.y; hb.y = h4.y; acc = __builtin_elementwise_fma(hb, wv[4*qq+1], acc);
                hb.x = h4.z; hb.y = h4.z; acc = __builtin_elementwise_fma(hb, wv[4*qq+2], acc);
                hb.x = h4.w; hb.y = h4.w; acc = __builtin_elementwise_fma(hb, wv[4*qq+3], acc);
            }
            *(v2f*)&partb[0][s][lane * 2] = acc;
        }
        __syncthreads();

        // ---- red0 + publish0 (reducers) / pf0' issue (remote waves) ----
        if (is_reducer) {
            float ssum = partb[0][0][q] + partb[0][1][q] + partb[0][2][q] + partb[0][3][q]
                       + partb[0][4][q] + partb[0][5][q] + partb[0][6][q] + partb[0][7][q];
            const float hv = tanhf(xw0 + ssum);
            if (t < TSTEPS - 1) {
                const unsigned long long v =
                    ((unsigned long long)(unsigned)(t + 1) << 32) |
                    (unsigned long long)__float_as_uint(hv);
                __hip_atomic_store(&cb0[mycol], v,
                                   __ATOMIC_RELAXED, __HIP_MEMORY_SCOPE_AGENT);
            }
            hslice[0][s][lane] = hv;         // slot == mycol for reducers
            o0[(size_t)t * DH + mycol] = hv;
            if (t < TSTEPS - 1)
                xw0 = o0[(size_t)(t + 1) * DH + mycol];   // overlaps task1
        } else if (t < TSTEPS - 1) {
            // prefetch seq0's h_t slot for next step (checked at fill0@t+1)
            pf0 = __hip_atomic_load(&cb0[slot], __ATOMIC_RELAXED,
                                    __HIP_MEMORY_SCOPE_AGENT);
        }

        // ---- fill1: hslice[1] <- h_{t-1}(seq1) ----
        if (t > 0 && !is_reducer) {
            unsigned long long v = pf1;
            while ((unsigned)(v >> 32) < wantP)
                v = __hip_atomic_load(&pb1[slot], __ATOMIC_RELAXED,
                                      __HIP_MEMORY_SCOPE_AGENT);
            hslice[1][s][lane] = __uint_as_float((unsigned)v);
        }

        // ---- task1 FMA: partials for seq1 ----
        {
            v2f acc = {0.0f, 0.0f};
            #pragma unroll
            for (int qq = 0; qq < 16; ++qq) {
                const float4 h4 = *(const float4*)&hslice[1][s][qq * 4];
                v2f hb;
                hb.x = h4.x; hb.y = h4.x; acc = __builtin_elementwise_fma(hb, wv[4*qq+0], acc);
                hb.x = h4.y; hb.y = h4.y; acc = __builtin_elementwise_fma(hb, wv[4*qq+1], acc);
                hb.x = h4.z; hb.y = h4.z; acc = __builtin_elementwise_fma(hb, wv[4*qq+2], acc);
                hb.x = h4.w; hb.y = h4.w; acc = __builtin_elementwise_fma(hb, wv[4*qq+3], acc);
            }
            *(v2f*)&partb[1][s][lane * 2] = acc;
        }
        __syncthreads();

        // ---- red1 + publish1 ----
        if (is_reducer) {
            float ssum = partb[1][0][q] + partb[1][1][q] + partb[1][2][q] + partb[1][3][q]
                       + partb[1][4][q] + partb[1][5][q] + partb[1][6][q] + partb[1][7][q];
            const float hv = tanhf(xw1 + ssum);
            if (t < TSTEPS - 1) {
                const unsigned long long v =
                    ((unsigned long long)(unsigned)(t + 1) << 32) |
                    (unsigned long long)__float_as_uint(hv);
                __hip_atomic_store(&cb1[mycol], v,
                                   __ATOMIC_RELAXED, __HIP_MEMORY_SCOPE_AGENT);
            }
            hslice[1][s][lane] = hv;
            o1[(size_t)t * DH + mycol] = hv;
            if (t < TSTEPS - 1)
                xw1 = o1[(size_t)(t + 1) * DH + mycol];   // overlaps next task0
        }
        // remote waves' pf1 for next step is issued at next iteration's fill0
        // (budget: sibling publish1@t -> our fill1@t+1 is ~1 task + transit).
    }
}

// ---------------- Last-resort fallback (R1 kernel) --------------------------
__global__ __launch_bounds__(1024) void rnn_rec(
    const float* __restrict__ Wh,
    const float* __restrict__ h0,
    float* __restrict__ out)
{
    __shared__ float hsh[DH];
    __shared__ float part[8][DH];

    const int n     = blockIdx.x;
    const int tid   = threadIdx.x;
    const int jgrp  = tid & 127;
    const int ks    = tid >> 7;
    const int kbase = ks * 64;

    if (tid < DH) hsh[tid] = h0[(size_t)n * DH + tid];
    __syncthreads();

    const float4* __restrict__ Wh4 = (const float4*)Wh;
    float* __restrict__ outn = out + (size_t)n * TSTEPS * DH;

    float xw_cur = (tid < DH) ? outn[tid] : 0.0f;

    for (int t = 0; t < TSTEPS; ++t) {
        float xw_next = 0.0f;
        if (tid < DH && t < TSTEPS - 1) xw_next = outn[(size_t)(t + 1) * DH + tid];

        float4 acc = {0.0f, 0.0f, 0.0f, 0.0f};
        #pragma unroll 8
        for (int k = 0; k < 64; ++k) {
            const float hk = hsh[kbase + k];
            const float4 w = Wh4[(size_t)(kbase + k) * 128 + jgrp];
            acc.x += hk * w.x; acc.y += hk * w.y;
            acc.z += hk * w.z; acc.w += hk * w.w;
        }
        *(float4*)&part[ks][jgrp * 4] = acc;
        __syncthreads();

        if (tid < DH) {
            const int j = tid;
            float sum = part[0][j] + part[1][j] + part[2][j] + part[3][j]
                      + part[4][j] + part[5][j] + part[6][j] + part[7][j];
            const float hv = tanhf(xw_cur + sum);
            hsh[j] = hv;
            outn[(size_t)t * DH + j] = hv;
            xw_cur = xw_next;
        }
        __syncthreads();
    }
}

extern "C" void kernel_launch(void* const* d_in, const int* in_sizes, int n_in,
                              void* d_out, int out_size, void* d_ws, size_t ws_size,
                              hipStream_t stream) {
    const float* x  = (const float*)d_in[0];  // (64, 512, 512)
    const float* h0 = (const float*)d_in[1];  // (64, 512)
    const float* Wx = (const float*)d_in[2];  // (512, 512)
    const float* Wh = (const float*)d_in[3];  // (512, 512)
    const float* b  = (const float*)d_in[4];  // (512,)
    float* out = (float*)d_out;               // (64, 512, 512)

    // Kernel A: xw = x @ Wx + b, written into d_out.
    xw_gemm<<<dim3(MTOT / 64, DH / 64), 256, 0, stream>>>(x, Wx, b, out);

    // Workspace: hbuf = (2, 64, 512) u64 tagged slots = 512 KB, zeroed per
    // launch (tag 0 < 1 => step-0/1 polls can't see stale; graph-replay safe).
    const size_t hbuf_bytes = (size_t)2 * NSEQ * DH * sizeof(unsigned long long);
    if (ws_size >= hbuf_bytes) {
        unsigned long long* hbuf = (unsigned long long*)d_ws;
        hipMemsetAsync(hbuf, 0, hbuf_bytes, stream);
        rnn_rec7<<<128, 512, 0, stream>>>(Wh, h0, out, hbuf);
    } else {
        rnn_rec<<<NSEQ, 1024, 0, stream>>>(Wh, h0, out);
    }
}

// Round 8
// 981.596 us; speedup vs baseline: 24.6204x; 1.3656x over previous
//
#include <hip/hip_runtime.h>
#include <hip/hip_bf16.h>
#include <cmath>

// Problem: N=64, T=512, D=512, H=512
//   xw = x @ Wx + b                 (parallel GEMM, kernel A -> d_out)
//   h_t = tanh(xw_t + h_{t-1} @ Wh) (sequential, kernel B)
//
// R8 = R5 structure (4 wgs/seq, 128-col register-resident Wh slices, tagged
// 8B {tag,h} words, causality-safe double buffer) with the exchange moved to
// the XCD-local L2 via ATOMIC RMW:
//  - R6 forensics: placement heuristic works and producer stores reach the
//    shared L2; the failure was consumer plain/sc0 loads spinning on stale L1.
//  - Atomic RMWs execute in the TCC (L2) -- vector L1 has no atomic units --
//    so fetch_or(0) is an architecturally guaranteed L1-bypass read.
//  - Producer: atomic_exchange (RELAXED, WORKGROUP scope => no cross-XCD bit,
//    local-L2 execution, 8B atomic) into hbufA + agent-scope store into hbufB.
//  - Consumer: capped fetch_or(0) polls on hbufA (1024 @ t=0, 256 later);
//    on timeout latch useL3 and poll hbufB (R5's proven path). Hang-proof;
//    worst case ~ R5 + 150 us. Tag monotonicity => wrong data impossible.

#define DH     512
#define NSEQ   64
#define TSTEPS 512
#define MTOT   32768   // N*T

typedef float v2f __attribute__((ext_vector_type(2)));

// ---------------- Kernel A: xw = x @ Wx + b  (fp32 LDS-tiled GEMM) ----------
__global__ __launch_bounds__(256) void xw_gemm(
    const float* __restrict__ X,    // (32768, 512)
    const float* __restrict__ Wx,   // (512, 512)
    const float* __restrict__ b,    // (512,)
    float* __restrict__ XW)         // (32768, 512) == d_out
{
    __shared__ float As[16][64];
    __shared__ float Bs[16][64];

    const int bm = blockIdx.x * 64;
    const int bn = blockIdx.y * 64;
    const int tid = threadIdx.x;
    const int tr = tid >> 4;
    const int tc = tid & 15;

    float acc[4][4] = {};

    for (int k0 = 0; k0 < DH; k0 += 16) {
        {
            int m  = tid >> 2;
            int kk = (tid & 3) * 4;
            const float4 v = *(const float4*)&X[(size_t)(bm + m) * DH + k0 + kk];
            As[kk + 0][m] = v.x; As[kk + 1][m] = v.y;
            As[kk + 2][m] = v.z; As[kk + 3][m] = v.w;
        }
        {
            int k  = tid >> 4;
            int j4 = (tid & 15) * 4;
            *(float4*)&Bs[k][j4] = *(const float4*)&Wx[(size_t)(k0 + k) * DH + bn + j4];
        }
        __syncthreads();

        #pragma unroll
        for (int k = 0; k < 16; ++k) {
            float a0 = As[k][tr * 4 + 0], a1 = As[k][tr * 4 + 1];
            float a2 = As[k][tr * 4 + 2], a3 = As[k][tr * 4 + 3];
            float b0 = Bs[k][tc * 4 + 0], b1 = Bs[k][tc * 4 + 1];
            float b2 = Bs[k][tc * 4 + 2], b3 = Bs[k][tc * 4 + 3];
            acc[0][0] += a0 * b0; acc[0][1] += a0 * b1; acc[0][2] += a0 * b2; acc[0][3] += a0 * b3;
            acc[1][0] += a1 * b0; acc[1][1] += a1 * b1; acc[1][2] += a1 * b2; acc[1][3] += a1 * b3;
            acc[2][0] += a2 * b0; acc[2][1] += a2 * b1; acc[2][2] += a2 * b2; acc[2][3] += a2 * b3;
            acc[3][0] += a3 * b0; acc[3][1] += a3 * b1; acc[3][2] += a3 * b2; acc[3][3] += a3 * b3;
        }
        __syncthreads();
    }

    #pragma unroll
    for (int i = 0; i < 4; ++i) {
        const size_t row = (size_t)(bm + tr * 4 + i);
        #pragma unroll
        for (int j = 0; j < 4; ++j) {
            const int col = bn + tc * 4 + j;
            XW[row * DH + col] = acc[i][j] + b[col];
        }
    }
}

// ---------------- Kernel B (R8): 4 wgs/seq, L2-atomic exchange --------------
// 256 wgs x 512 thr. bid -> xcd=bid&7, seq=xcd*8+((bid>>3)&7), part=bid>>6:
// the 4 parts of a seq have bids b, b+64, b+128, b+192 (same bid%8 -> same
// XCD under round-robin; confirmed working by R6 forensics).
// Waves: lane=tid&63, s=tid>>6; wave s holds Wh k-slice [s*64,+64) x its
// wg's 128 cols in regs. Reducer waves (s==2*part+r): own reduce output ==
// own FMA h-slice (slot==mycol) -> never leaves the wg.
__global__ __launch_bounds__(512, 2) void rnn_rec8(
    const float* __restrict__ Wh,             // (512, 512)
    const float* __restrict__ h0,             // (64, 512)
    float* __restrict__ out,                  // (64, 512, 512); xw on entry
    unsigned long long* __restrict__ hbufA,   // (2,64,512) L2-path tagged h
    unsigned long long* __restrict__ hbufB)   // (2,64,512) L3-path tagged h
{
    __shared__ float hslice[8][64];          // wave-private h slices
    __shared__ float partb[2][8][128];       // double-buffered partials

    const int bid  = blockIdx.x;
    const int xcd  = bid & 7;
    const int idx  = bid >> 3;
    const int seq  = xcd * 8 + (idx & 7);
    const int part = idx >> 3;               // 0..3
    const int tid  = threadIdx.x;
    const int lane = tid & 63;
    const int s    = tid >> 6;                // wave 0..7
    const int colbase = part * 128;
    const int c0   = colbase + lane * 2;

    // ---- one-time: weight slice into registers, pinned ----
    v2f wv[64];
    #pragma unroll
    for (int k = 0; k < 64; ++k)
        wv[k] = *(const v2f*)&Wh[(size_t)(s * 64 + k) * DH + c0];
    #pragma unroll
    for (int k = 0; k < 64; ++k)
        asm volatile("" : "+v"(wv[k]));

    const int rwave = s - 2 * part;
    const bool is_reducer = (rwave == 0) | (rwave == 1);
    const int q     = rwave * 64 + lane;      // col within part (reducer only)
    const int mycol = colbase + q;            // == slot for reducer waves
    const int slot  = s * 64 + lane;          // h index this lane feeds

    hslice[s][lane] = h0[(size_t)seq * DH + slot];

    float* __restrict__ outn = out + (size_t)seq * TSTEPS * DH;
    float xw_cur = is_reducer ? outn[mycol] : 0.0f;

    unsigned long long* const A0 = &hbufA[((size_t)0 * NSEQ + seq) * DH];
    unsigned long long* const A1 = &hbufA[((size_t)1 * NSEQ + seq) * DH];
    unsigned long long* const B0 = &hbufB[((size_t)0 * NSEQ + seq) * DH];
    unsigned long long* const B1 = &hbufB[((size_t)1 * NSEQ + seq) * DH];

    bool useL3 = false;

    for (int t = 0; t < TSTEPS; ++t) {
        const int buf = t & 1;

        // ---- phase A: partial FMA over own k-slice (all 8 waves) ----
        v2f acc = {0.0f, 0.0f};
        #pragma unroll
        for (int qq = 0; qq < 16; ++qq) {
            const float4 h4 = *(const float4*)&hslice[s][qq * 4];
            v2f hb;
            hb.x = h4.x; hb.y = h4.x; acc = __builtin_elementwise_fma(hb, wv[4*qq+0], acc);
            hb.x = h4.y; hb.y = h4.y; acc = __builtin_elementwise_fma(hb, wv[4*qq+1], acc);
            hb.x = h4.z; hb.y = h4.z; acc = __builtin_elementwise_fma(hb, wv[4*qq+2], acc);
            hb.x = h4.w; hb.y = h4.w; acc = __builtin_elementwise_fma(hb, wv[4*qq+3], acc);
        }
        *(v2f*)&partb[buf][s][lane * 2] = acc;
        __syncthreads();   // the only barrier per step

        unsigned long long* const hbA = buf ? A1 : A0;
        unsigned long long* const hbB = buf ? B1 : B0;

        if (is_reducer) {
            float ssum = partb[buf][0][q] + partb[buf][1][q]
                       + partb[buf][2][q] + partb[buf][3][q]
                       + partb[buf][4][q] + partb[buf][5][q]
                       + partb[buf][6][q] + partb[buf][7][q];
            const float hval = tanhf(xw_cur + ssum);
            if (t < TSTEPS - 1) {
                const unsigned long long v =
                    ((unsigned long long)(unsigned)(t + 1) << 32) |
                    (unsigned long long)__float_as_uint(hval);
                // L2 fast publish: workgroup-scope RMW executes in local TCC,
                // 8B-atomic (no tearing), bypasses L1 by construction.
                (void)__hip_atomic_exchange(&hbA[mycol], v, __ATOMIC_RELAXED,
                                            __HIP_MEMORY_SCOPE_WORKGROUP);
                // L3 guaranteed publish (cross-XCD safety net).
                __hip_atomic_store(&hbB[mycol], v, __ATOMIC_RELAXED,
                                   __HIP_MEMORY_SCOPE_AGENT);
            }
            hslice[s][lane] = hval;          // own next-step data (slot==mycol)
            outn[(size_t)t * DH + mycol] = hval;
            if (t < TSTEPS - 1)
                xw_cur = outn[(size_t)(t + 1) * DH + mycol];
        } else if (t < TSTEPS - 1) {
            const unsigned want = (unsigned)(t + 1);
            unsigned long long v = 0;
            bool got = false;
            if (!useL3) {
                // Atomic-RMW poll: serviced by L2, never L1 -> no stale spin.
                int cap = (t == 0) ? 1024 : 256;
                do {
                    v = __hip_atomic_fetch_or(&hbA[slot], 0ull, __ATOMIC_RELAXED,
                                              __HIP_MEMORY_SCOPE_WORKGROUP);
                    got = ((unsigned)(v >> 32) >= want);
                } while (!got && --cap > 0);
                if (__any(!got)) useL3 = true;   // wave-uniform latch
            }
            if (!got) {
                do {
                    v = __hip_atomic_load(&hbB[slot], __ATOMIC_RELAXED,
                                          __HIP_MEMORY_SCOPE_AGENT);
                } while ((unsigned)(v >> 32) < want);
            }
            hslice[s][lane] = __uint_as_float((unsigned)v);
        }
        // no second barrier: hslice wave-private, partb double-buffered
    }
}

// ---------------- Mid fallback (R5 kernel, L3-only) -------------------------
__global__ __launch_bounds__(512, 2) void rnn_rec5(
    const float* __restrict__ Wh,
    const float* __restrict__ h0,
    float* __restrict__ out,
    unsigned long long* __restrict__ hbuf)
{
    __shared__ float hslice[8][64];
    __shared__ float partb[2][8][128];

    const int bid  = blockIdx.x;
    const int xcd  = bid & 7;
    const int idx  = bid >> 3;
    const int seq  = xcd * 8 + (idx & 7);
    const int part = idx >> 3;
    const int tid  = threadIdx.x;
    const int lane = tid & 63;
    const int s    = tid >> 6;
    const int colbase = part * 128;
    const int c0   = colbase + lane * 2;

    v2f wv[64];
    #pragma unroll
    for (int k = 0; k < 64; ++k)
        wv[k] = *(const v2f*)&Wh[(size_t)(s * 64 + k) * DH + c0];
    #pragma unroll
    for (int k = 0; k < 64; ++k)
        asm volatile("" : "+v"(wv[k]));

    const int rwave = s - 2 * part;
    const bool is_reducer = (rwave == 0) | (rwave == 1);
    const int q     = rwave * 64 + lane;
    const int mycol = colbase + q;
    const int slot  = s * 64 + lane;

    hslice[s][lane] = h0[(size_t)seq * DH + slot];

    float* __restrict__ outn = out + (size_t)seq * TSTEPS * DH;
    float xw_cur = is_reducer ? outn[mycol] : 0.0f;

    for (int t = 0; t < TSTEPS; ++t) {
        const int buf = t & 1;
        v2f acc = {0.0f, 0.0f};
        #pragma unroll
        for (int qq = 0; qq < 16; ++qq) {
            const float4 h4 = *(const float4*)&hslice[s][qq * 4];
            v2f hb;
            hb.x = h4.x; hb.y = h4.x; acc = __builtin_elementwise_fma(hb, wv[4*qq+0], acc);
            hb.x = h4.y; hb.y = h4.y; acc = __builtin_elementwise_fma(hb, wv[4*qq+1], acc);
            hb.x = h4.z; hb.y = h4.z; acc = __builtin_elementwise_fma(hb, wv[4*qq+2], acc);
            hb.x = h4.w; hb.y = h4.w; acc = __builtin_elementwise_fma(hb, wv[4*qq+3], acc);
        }
        *(v2f*)&partb[buf][s][lane * 2] = acc;
        __syncthreads();

        unsigned long long* hb64 = &hbuf[((size_t)buf * NSEQ + seq) * DH];
        if (is_reducer) {
            float ssum = partb[buf][0][q] + partb[buf][1][q]
                       + partb[buf][2][q] + partb[buf][3][q]
                       + partb[buf][4][q] + partb[buf][5][q]
                       + partb[buf][6][q] + partb[buf][7][q];
            const float hval = tanhf(xw_cur + ssum);
            if (t < TSTEPS - 1) {
                const unsigned long long v =
                    ((unsigned long long)(unsigned)(t + 1) << 32) |
                    (unsigned long long)__float_as_uint(hval);
                __hip_atomic_store(&hb64[mycol], v,
                                   __ATOMIC_RELAXED, __HIP_MEMORY_SCOPE_AGENT);
            }
            hslice[s][lane] = hval;
            outn[(size_t)t * DH + mycol] = hval;
            if (t < TSTEPS - 1)
                xw_cur = outn[(size_t)(t + 1) * DH + mycol];
        } else if (t < TSTEPS - 1) {
            unsigned long long v;
            do {
                v = __hip_atomic_load(&hb64[slot], __ATOMIC_RELAXED,
                                      __HIP_MEMORY_SCOPE_AGENT);
            } while ((unsigned)(v >> 32) < (unsigned)(t + 1));
            hslice[s][lane] = __uint_as_float((unsigned)v);
        }
    }
}

// ---------------- Last-resort fallback (R1 kernel) --------------------------
__global__ __launch_bounds__(1024) void rnn_rec(
    const float* __restrict__ Wh,
    const float* __restrict__ h0,
    float* __restrict__ out)
{
    __shared__ float hsh[DH];
    __shared__ float part[8][DH];

    const int n     = blockIdx.x;
    const int tid   = threadIdx.x;
    const int jgrp  = tid & 127;
    const int ks    = tid >> 7;
    const int kbase = ks * 64;

    if (tid < DH) hsh[tid] = h0[(size_t)n * DH + tid];
    __syncthreads();

    const float4* __restrict__ Wh4 = (const float4*)Wh;
    float* __restrict__ outn = out + (size_t)n * TSTEPS * DH;

    float xw_cur = (tid < DH) ? outn[tid] : 0.0f;

    for (int t = 0; t < TSTEPS; ++t) {
        float xw_next = 0.0f;
        if (tid < DH && t < TSTEPS - 1) xw_next = outn[(size_t)(t + 1) * DH + tid];

        float4 acc = {0.0f, 0.0f, 0.0f, 0.0f};
        #pragma unroll 8
        for (int k = 0; k < 64; ++k) {
            const float hk = hsh[kbase + k];
            const float4 w = Wh4[(size_t)(kbase + k) * 128 + jgrp];
            acc.x += hk * w.x; acc.y += hk * w.y;
            acc.z += hk * w.z; acc.w += hk * w.w;
        }
        *(float4*)&part[ks][jgrp * 4] = acc;
        __syncthreads();

        if (tid < DH) {
            const int j = tid;
            float sum = part[0][j] + part[1][j] + part[2][j] + part[3][j]
                      + part[4][j] + part[5][j] + part[6][j] + part[7][j];
            const float hv = tanhf(xw_cur + sum);
            hsh[j] = hv;
            outn[(size_t)t * DH + j] = hv;
            xw_cur = xw_next;
        }
        __syncthreads();
    }
}

extern "C" void kernel_launch(void* const* d_in, const int* in_sizes, int n_in,
                              void* d_out, int out_size, void* d_ws, size_t ws_size,
                              hipStream_t stream) {
    const float* x  = (const float*)d_in[0];  // (64, 512, 512)
    const float* h0 = (const float*)d_in[1];  // (64, 512)
    const float* Wx = (const float*)d_in[2];  // (512, 512)
    const float* Wh = (const float*)d_in[3];  // (512, 512)
    const float* b  = (const float*)d_in[4];  // (512,)
    float* out = (float*)d_out;               // (64, 512, 512)

    // Kernel A: xw = x @ Wx + b, written into d_out.
    xw_gemm<<<dim3(MTOT / 64, DH / 64), 256, 0, stream>>>(x, Wx, b, out);

    // Workspace: hbufA | hbufB, each (2,64,512) u64 = 512 KB. Zeroed per
    // launch so step-0 polls see tag 0 < 1 (graph-replay deterministic).
    const size_t one = (size_t)2 * NSEQ * DH * sizeof(unsigned long long);
    if (ws_size >= 2 * one) {
        unsigned long long* hbufA = (unsigned long long*)d_ws;
        unsigned long long* hbufB = hbufA + 2 * NSEQ * DH;
        hipMemsetAsync(d_ws, 0, 2 * one, stream);
        rnn_rec8<<<256, 512, 0, stream>>>(Wh, h0, out, hbufA, hbufB);
    } else if (ws_size >= one) {
        unsigned long long* hbuf = (unsigned long long*)d_ws;
        hipMemsetAsync(hbuf, 0, one, stream);
        rnn_rec5<<<256, 512, 0, stream>>>(Wh, h0, out, hbuf);
    } else {
        rnn_rec<<<NSEQ, 1024, 0, stream>>>(Wh, h0, out);
    }
}